// Round 6
// baseline (338.736 us; speedup 1.0000x reference)
//
#include <hip/hip_runtime.h>
#include <stdint.h>

#define B_  2
#define S_  2048
#define D_  1024
#define H_  16
#define HD_ 64
#define TOK (B_*S_)   // 4096

typedef __bf16 bf16x8 __attribute__((ext_vector_type(8)));
typedef __bf16 bf16x4 __attribute__((ext_vector_type(4)));
typedef float  f32x4  __attribute__((ext_vector_type(4)));

static_assert(sizeof(bf16x8) == 16, "bf16x8 must be 16B");
static_assert(sizeof(bf16x4) == 8,  "bf16x4 must be 8B");

__device__ __forceinline__ float fexp2(float x) { return __builtin_amdgcn_exp2f(x); }

__device__ __forceinline__ f32x4 mfma16(bf16x8 a, bf16x8 b, f32x4 c) {
    return __builtin_amdgcn_mfma_f32_16x16x32_bf16(a, b, c, 0, 0, 0);
}

// ---------------------------------------------------------------------------
// K0a: Wo [1024(in)][1024(out)] fp32 -> WoT [out][in] bf16. grid (16,16).
// ---------------------------------------------------------------------------
__global__ __launch_bounds__(256) void k_transpose_wo(
    const float* __restrict__ Wo, unsigned short* __restrict__ WoT)
{
    __shared__ float t[64][65];
    const int i0 = blockIdx.x * 64;
    const int o0 = blockIdx.y * 64;
    const int tid = threadIdx.x;
    #pragma unroll
    for (int p = 0; p < 16; ++p) {
        int idx = tid + p * 256;
        int r = idx >> 6, c = idx & 63;
        t[r][c] = Wo[(size_t)(i0 + r) * D_ + o0 + c];
    }
    __syncthreads();
    #pragma unroll
    for (int p = 0; p < 16; ++p) {
        int idx = tid + p * 256;
        int r = idx >> 6, c = idx & 63;
        reinterpret_cast<__bf16*>(WoT)[(size_t)(o0 + r) * D_ + i0 + c] = (__bf16)t[c][r];
    }
}

// ---------------------------------------------------------------------------
// K0b: Wq/Wk/Wv [H][d][e] fp32 -> WT [z][h][e][d] bf16. grid (H,3), block 256.
// ---------------------------------------------------------------------------
__global__ __launch_bounds__(256) void k_transpose_w(
    const float* __restrict__ Wq, const float* __restrict__ Wk,
    const float* __restrict__ Wv, unsigned short* __restrict__ WT)
{
    __shared__ float t[64][65];
    const int h = blockIdx.x, z = blockIdx.y;
    const float* W = (z == 0) ? Wq : (z == 1) ? Wk : Wv;
    const int tid = threadIdx.x;
    #pragma unroll
    for (int p = 0; p < 4; ++p) {
        int idx = tid + p * 256;
        int r = idx >> 4, c4 = (idx & 15) * 4;
        *reinterpret_cast<float4*>(&t[r][c4]) =
            *reinterpret_cast<const float4*>(&W[h * 4096 + r * 64 + c4]);
    }
    __syncthreads();
    const int e = tid >> 2, db = (tid & 3) * 16;
    __bf16* out = reinterpret_cast<__bf16*>(WT) + ((size_t)(z * H_ + h) * 64 + e) * 64 + db;
    #pragma unroll
    for (int jj = 0; jj < 2; ++jj) {
        bf16x8 v;
        #pragma unroll
        for (int j = 0; j < 8; ++j) v[j] = (__bf16)t[db + jj * 8 + j][e];
        *reinterpret_cast<bf16x8*>(out + jj * 8) = v;
    }
}

// ---------------------------------------------------------------------------
// K1 (v3, unchanged): QKV projection, fused z-loop, MFMA.
// grid (TOK/128, H), block 256.
// ---------------------------------------------------------------------------
__global__ __launch_bounds__(256) void k_qkv(
    const float* __restrict__ X, const unsigned short* __restrict__ WT,
    const float* __restrict__ bq, const float* __restrict__ bk,
    const float* __restrict__ bv,
    unsigned short* __restrict__ Qo, unsigned short* __restrict__ Ko,
    unsigned short* __restrict__ Vt)
{
    __shared__ unsigned short Xl[128 * 64];
    __shared__ unsigned short Wl[3][64 * 64];

    const int tid  = threadIdx.x;
    const int lane = tid & 63, w = tid >> 6;
    const int g = lane >> 4, q = lane & 15;
    const int tok0 = blockIdx.x * 128;
    const int h    = blockIdx.y;

    #pragma unroll
    for (int i = 0; i < 4; ++i) {
        int c = tid + 256 * i;
        int row = c >> 3, slot = c & 7;
        const float* src = &X[(size_t)(tok0 + row) * D_ + h * HD_ + slot * 8];
        float4 x0 = *reinterpret_cast<const float4*>(src);
        float4 x1 = *reinterpret_cast<const float4*>(src + 4);
        bf16x8 v = { (__bf16)x0.x, (__bf16)x0.y, (__bf16)x0.z, (__bf16)x0.w,
                     (__bf16)x1.x, (__bf16)x1.y, (__bf16)x1.z, (__bf16)x1.w };
        *reinterpret_cast<bf16x8*>(
            reinterpret_cast<char*>(Xl) + row * 128 + ((slot ^ (row & 7)) * 16)) = v;
    }
    #pragma unroll
    for (int zz = 0; zz < 3; ++zz) {
        #pragma unroll
        for (int i = 0; i < 2; ++i) {
            int c = tid + 256 * i;
            int e = c >> 3, slot = c & 7;
            bf16x8 v = *reinterpret_cast<const bf16x8*>(
                &WT[((size_t)(zz * H_ + h) * 64 + e) * 64 + slot * 8]);
            *reinterpret_cast<bf16x8*>(
                reinterpret_cast<char*>(Wl[zz]) + e * 128 + ((slot ^ (e & 7)) * 16)) = v;
        }
    }
    __syncthreads();

    const float scq = 0.18033688011112042f;  // log2(e)/8
    const int b  = tok0 >> 11;
    const int sb = (tok0 & (S_ - 1)) + w * 32;

    #pragma unroll
    for (int z = 0; z < 3; ++z) {
        const float* bb = (z == 0) ? bq : (z == 1) ? bk : bv;
        f32x4 acc[2][4] = {};
        #pragma unroll
        for (int s = 0; s < 2; ++s) {
            bf16x8 af[2], bfr[4];
            #pragma unroll
            for (int am = 0; am < 2; ++am) {
                int row  = w * 32 + am * 16 + q;
                int slot = (s * 4 + g) ^ (row & 7);
                af[am] = *reinterpret_cast<const bf16x8*>(
                    reinterpret_cast<const char*>(Xl) + row * 128 + slot * 16);
            }
            #pragma unroll
            for (int bn = 0; bn < 4; ++bn) {
                int row  = bn * 16 + q;
                int slot = (s * 4 + g) ^ (row & 7);
                bfr[bn] = *reinterpret_cast<const bf16x8*>(
                    reinterpret_cast<const char*>(Wl[z]) + row * 128 + slot * 16);
            }
            if (z == 2) {
                #pragma unroll
                for (int am = 0; am < 2; ++am)
                    #pragma unroll
                    for (int bn = 0; bn < 4; ++bn)
                        acc[am][bn] = mfma16(af[am], bfr[bn], acc[am][bn]);
            } else {
                #pragma unroll
                for (int am = 0; am < 2; ++am)
                    #pragma unroll
                    for (int bn = 0; bn < 4; ++bn)
                        acc[am][bn] = mfma16(bfr[bn], af[am], acc[am][bn]);
            }
        }
        if (z == 2) {
            #pragma unroll
            for (int bn = 0; bn < 4; ++bn) {
                int e = bn * 16 + q;
                float bia = bb[h * HD_ + e];
                #pragma unroll
                for (int am = 0; am < 2; ++am) {
                    int s4 = sb + am * 16 + 4 * g;
                    bf16x4 ov = { (__bf16)(acc[am][bn][0] + bia), (__bf16)(acc[am][bn][1] + bia),
                                  (__bf16)(acc[am][bn][2] + bia), (__bf16)(acc[am][bn][3] + bia) };
                    *reinterpret_cast<bf16x4*>(
                        &Vt[((size_t)(b * H_ + h) * HD_ + e) * S_ + s4]) = ov;
                }
            }
        } else {
            const float sc = (z == 0) ? scq : 1.0f;
            unsigned short* dst = (z == 0) ? Qo : Ko;
            #pragma unroll
            for (int bn = 0; bn < 4; ++bn) {
                float4 bia4 = *reinterpret_cast<const float4*>(&bb[h * HD_ + bn * 16 + 4 * g]);
                #pragma unroll
                for (int am = 0; am < 2; ++am) {
                    int tok = sb + am * 16 + q;
                    bf16x4 ov = { (__bf16)((acc[am][bn][0] + bia4.x) * sc),
                                  (__bf16)((acc[am][bn][1] + bia4.y) * sc),
                                  (__bf16)((acc[am][bn][2] + bia4.z) * sc),
                                  (__bf16)((acc[am][bn][3] + bia4.w) * sc) };
                    *reinterpret_cast<bf16x4*>(
                        &dst[((size_t)(b * H_ + h) * S_ + tok) * HD_ + bn * 16 + 4 * g]) = ov;
                }
            }
        }
    }
}

// ---------------------------------------------------------------------------
// K2 (v4): flash attention, NO K/V LDS staging, NO barriers.
//  - K/V per (b,h) = 512 KB -> L2-resident; MFMA fragments read DIRECTLY from
//    global (each frag = 16 rows x 64B coalesced b128 pattern).
//  - Waves fully independent; only per-wave P roundtrip through LDS.
//  - XCD-bijective work remap: XCD x (= linear%8) serves bh in [4x,4x+4),
//    so each XCD L2 caches only 2 MB of KV.
//  - Swapped QK^T; defer-max (T13); setprio around MFMA (T5, m191).
// Block = 4 waves x 16 q-rows; 32 keys/iter. grid (32, 32), block 256.
// ---------------------------------------------------------------------------
__global__ __launch_bounds__(256) void k_attn(
    const unsigned short* __restrict__ Q,
    const unsigned short* __restrict__ K,
    const unsigned short* __restrict__ V,
    unsigned short* __restrict__ O)
{
    __shared__ unsigned short P_lds[4][16 * 40];   // 5120 B

    const int L  = blockIdx.x + (int)gridDim.x * blockIdx.y;  // 0..1023
    const int bh = (L & 7) * 4 + ((L >> 3) & 3);              // XCD-grouped
    const int sb = L >> 5;

    const unsigned short* Qp = Q + (size_t)bh * S_ * HD_;
    const unsigned short* Kp = K + (size_t)bh * S_ * HD_;
    const unsigned short* Vp = V + (size_t)bh * HD_ * S_;

    const int tid  = threadIdx.x;
    const int lane = tid & 63, w = tid >> 6;
    const int g = lane >> 4, q = lane & 15;
    const int q0 = sb * 64 + w * 16;

    bf16x8 qf0 = *reinterpret_cast<const bf16x8*>(&Qp[(size_t)(q0 + q) * HD_ + 8 * g]);
    bf16x8 qf1 = *reinterpret_cast<const bf16x8*>(&Qp[(size_t)(q0 + q) * HD_ + 32 + 8 * g]);

    f32x4 acc0 = {0.f, 0.f, 0.f, 0.f}, acc1 = acc0, acc2 = acc0, acc3 = acc0;
    float m = -3.0e38f, lp = 0.0f;
    unsigned short* Pw = P_lds[w];

    // per-lane base pointers for direct-global fragment loads
    const unsigned short* kRow0 = Kp + (size_t)q * HD_ + 8 * g;         // key q
    const unsigned short* kRow1 = Kp + (size_t)(16 + q) * HD_ + 8 * g;  // key 16+q
    const unsigned short* vRow  = Vp + (size_t)q * S_ + 8 * g;          // dim q

    for (int kv = 0; kv < S_; kv += 32) {
        // ---- K/V fragments straight from global (L1/L2-served) ----
        const unsigned short* k0p = kRow0 + (size_t)kv * HD_;
        const unsigned short* k1p = kRow1 + (size_t)kv * HD_;
        bf16x8 k00 = *reinterpret_cast<const bf16x8*>(k0p);
        bf16x8 k01 = *reinterpret_cast<const bf16x8*>(k0p + 32);
        bf16x8 k10 = *reinterpret_cast<const bf16x8*>(k1p);
        bf16x8 k11 = *reinterpret_cast<const bf16x8*>(k1p + 32);
        bf16x8 vf0 = *reinterpret_cast<const bf16x8*>(vRow + kv);
        bf16x8 vf1 = *reinterpret_cast<const bf16x8*>(vRow + 16 * S_ + kv);
        bf16x8 vf2 = *reinterpret_cast<const bf16x8*>(vRow + 32 * S_ + kv);
        bf16x8 vf3 = *reinterpret_cast<const bf16x8*>(vRow + 48 * S_ + kv);

        // ---- S^T = K . Q^T ----
        f32x4 z4 = {0.f, 0.f, 0.f, 0.f};
        __builtin_amdgcn_s_setprio(1);
        f32x4 s0 = mfma16(k00, qf0, z4); s0 = mfma16(k01, qf1, s0);
        f32x4 s1 = mfma16(k10, qf0, z4); s1 = mfma16(k11, qf1, s1);
        __builtin_amdgcn_s_setprio(0);

        // ---- online softmax, defer-max fast path ----
        float pmax = fmaxf(fmaxf(fmaxf(s0[0], s0[1]), fmaxf(s0[2], s0[3])),
                           fmaxf(fmaxf(s1[0], s1[1]), fmaxf(s1[2], s1[3])));
        if (!__all(pmax - m <= 8.0f)) {
            float pm = pmax;
            pm = fmaxf(pm, __shfl_xor(pm, 16));
            pm = fmaxf(pm, __shfl_xor(pm, 32));
            float mn  = fmaxf(m, pm);
            float scl = fexp2(m - mn);
            m = mn;
            lp *= scl;
            acc0 *= scl; acc1 *= scl; acc2 *= scl; acc3 *= scl;
        }
        float p0 = fexp2(s0[0] - m), p1 = fexp2(s0[1] - m);
        float p2 = fexp2(s0[2] - m), p3 = fexp2(s0[3] - m);
        float p4 = fexp2(s1[0] - m), p5 = fexp2(s1[1] - m);
        float p6 = fexp2(s1[2] - m), p7 = fexp2(s1[3] - m);
        lp += ((p0 + p1) + (p2 + p3)) + ((p4 + p5) + (p6 + p7));

        // ---- P -> per-wave LDS (same-wave ordering, no barrier) ----
        bf16x4 pa = { (__bf16)p0, (__bf16)p1, (__bf16)p2, (__bf16)p3 };
        bf16x4 pb = { (__bf16)p4, (__bf16)p5, (__bf16)p6, (__bf16)p7 };
        *reinterpret_cast<bf16x4*>(&Pw[q * 40 + 4 * g])      = pa;
        *reinterpret_cast<bf16x4*>(&Pw[q * 40 + 16 + 4 * g]) = pb;
        bf16x8 pf = *reinterpret_cast<const bf16x8*>(&Pw[q * 40 + 8 * g]);

        // ---- O^T += V^T . P^T ----
        __builtin_amdgcn_s_setprio(1);
        acc0 = mfma16(vf0, pf, acc0);
        acc1 = mfma16(vf1, pf, acc1);
        acc2 = mfma16(vf2, pf, acc2);
        acc3 = mfma16(vf3, pf, acc3);
        __builtin_amdgcn_s_setprio(0);
    }

    // ---- epilogue ----
    lp += __shfl_xor(lp, 16);
    lp += __shfl_xor(lp, 32);
    const float inv = 1.0f / lp;
    const int b = bh >> 4, h = bh & 15;
    __bf16* Ob = reinterpret_cast<__bf16*>(O);
    size_t row = (size_t)(b * S_ + q0 + q) * D_ + h * HD_ + 4 * g;
    bf16x4 o0 = { (__bf16)(acc0[0]*inv), (__bf16)(acc0[1]*inv),
                  (__bf16)(acc0[2]*inv), (__bf16)(acc0[3]*inv) };
    bf16x4 o1 = { (__bf16)(acc1[0]*inv), (__bf16)(acc1[1]*inv),
                  (__bf16)(acc1[2]*inv), (__bf16)(acc1[3]*inv) };
    bf16x4 o2 = { (__bf16)(acc2[0]*inv), (__bf16)(acc2[1]*inv),
                  (__bf16)(acc2[2]*inv), (__bf16)(acc2[3]*inv) };
    bf16x4 o3 = { (__bf16)(acc3[0]*inv), (__bf16)(acc3[1]*inv),
                  (__bf16)(acc3[2]*inv), (__bf16)(acc3[3]*inv) };
    *reinterpret_cast<bf16x4*>(&Ob[row + 0])  = o0;
    *reinterpret_cast<bf16x4*>(&Ob[row + 16]) = o1;
    *reinterpret_cast<bf16x4*>(&Ob[row + 32]) = o2;
    *reinterpret_cast<bf16x4*>(&Ob[row + 48]) = o3;
}

// ---------------------------------------------------------------------------
// K3 (v3): out = O_attn(bf16) @ WoT + bo, fp32. 64x64 tile, BK=64, dbuf
// swizzled LDS, reg-staged async split. grid (TOK/64=64, D/64=16) = 1024
// blocks = 4/CU (occupancy fix vs v2's 256 blocks). Block 256, 4 waves,
// each a 32x32 quadrant.
// ---------------------------------------------------------------------------
__global__ __launch_bounds__(256) void k_out(
    const unsigned short* __restrict__ A,
    const unsigned short* __restrict__ Wt,
    const float* __restrict__ bo,
    float* __restrict__ C)
{
    __shared__ unsigned short Al[2][64 * 64];
    __shared__ unsigned short Bl[2][64 * 64];

    const int tid  = threadIdx.x;
    const int lane = tid & 63, w = tid >> 6;
    const int g = lane >> 4, q = lane & 15;
    const int wr = w & 1, wc = w >> 1;
    const int m0 = blockIdx.x * 64;
    const int n0 = blockIdx.y * 64;

    int    sbyte[2];
    size_t sgA[2], sgB[2];
    #pragma unroll
    for (int i = 0; i < 2; ++i) {
        int c = tid + 256 * i;
        int row = c >> 3, slot = c & 7;
        sbyte[i] = row * 128 + ((slot ^ (row & 7)) * 16);
        sgA[i] = (size_t)(m0 + row) * D_ + slot * 8;
        sgB[i] = (size_t)(n0 + row) * D_ + slot * 8;
    }

    uint4 ra[2], rb[2];
    #pragma unroll
    for (int i = 0; i < 2; ++i) {
        ra[i] = *reinterpret_cast<const uint4*>(A  + sgA[i]);
        rb[i] = *reinterpret_cast<const uint4*>(Wt + sgB[i]);
    }
    #pragma unroll
    for (int i = 0; i < 2; ++i) {
        *reinterpret_cast<uint4*>(reinterpret_cast<char*>(Al[0]) + sbyte[i]) = ra[i];
        *reinterpret_cast<uint4*>(reinterpret_cast<char*>(Bl[0]) + sbyte[i]) = rb[i];
    }
    __syncthreads();

    f32x4 acc[2][2] = {};
    const int NKT = D_ / 64;   // 16
    for (int kt = 0; kt < NKT; ++kt) {
        const int cur = kt & 1, nxt = cur ^ 1;
        const bool more = (kt + 1 < NKT);
        if (more) {
            #pragma unroll
            for (int i = 0; i < 2; ++i) {
                ra[i] = *reinterpret_cast<const uint4*>(A  + sgA[i] + (kt + 1) * 64);
                rb[i] = *reinterpret_cast<const uint4*>(Wt + sgB[i] + (kt + 1) * 64);
            }
        }
        const char* Ab = reinterpret_cast<const char*>(Al[cur]);
        const char* Bb = reinterpret_cast<const char*>(Bl[cur]);
        #pragma unroll
        for (int s = 0; s < 2; ++s) {
            bf16x8 af[2], bfr[2];
            #pragma unroll
            for (int am = 0; am < 2; ++am) {
                int row  = wr * 32 + am * 16 + q;
                int slot = (s * 4 + g) ^ (row & 7);
                af[am] = *reinterpret_cast<const bf16x8*>(Ab + row * 128 + slot * 16);
            }
            #pragma unroll
            for (int bn = 0; bn < 2; ++bn) {
                int row  = wc * 32 + bn * 16 + q;
                int slot = (s * 4 + g) ^ (row & 7);
                bfr[bn] = *reinterpret_cast<const bf16x8*>(Bb + row * 128 + slot * 16);
            }
            #pragma unroll
            for (int am = 0; am < 2; ++am)
                #pragma unroll
                for (int bn = 0; bn < 2; ++bn)
                    acc[am][bn] = mfma16(af[am], bfr[bn], acc[am][bn]);
        }
        if (more) {
            #pragma unroll
            for (int i = 0; i < 2; ++i) {
                *reinterpret_cast<uint4*>(reinterpret_cast<char*>(Al[nxt]) + sbyte[i]) = ra[i];
                *reinterpret_cast<uint4*>(reinterpret_cast<char*>(Bl[nxt]) + sbyte[i]) = rb[i];
            }
        }
        __syncthreads();
    }

    #pragma unroll
    for (int bn = 0; bn < 2; ++bn) {
        int n = n0 + wc * 32 + bn * 16 + q;
        float bia = bo[n];
        #pragma unroll
        for (int am = 0; am < 2; ++am) {
            int mbase = m0 + wr * 32 + am * 16 + 4 * g;
            #pragma unroll
            for (int j = 0; j < 4; ++j)
                C[(size_t)(mbase + j) * D_ + n] = acc[am][bn][j] + bia;
        }
    }
}

// ---------------------------------------------------------------------------
extern "C" void kernel_launch(void* const* d_in, const int* in_sizes, int n_in,
                              void* d_out, int out_size, void* d_ws, size_t ws_size,
                              hipStream_t stream)
{
    const float* X  = (const float*)d_in[0];
    const float* Wq = (const float*)d_in[1];
    const float* bq = (const float*)d_in[2];
    const float* Wk = (const float*)d_in[3];
    const float* bk = (const float*)d_in[4];
    const float* Wv = (const float*)d_in[5];
    const float* bv = (const float*)d_in[6];
    const float* Wo = (const float*)d_in[7];
    const float* bo = (const float*)d_in[8];
    float* out = (float*)d_out;

    unsigned short* ws = (unsigned short*)d_ws;
    const size_t QN = (size_t)B_ * H_ * S_ * HD_;     // 4M elements
    unsigned short* Qb    = ws;                       // 8 MB
    unsigned short* Kb    = ws + QN;                  // 8 MB
    unsigned short* Vtb   = ws + 2 * QN;              // 8 MB
    unsigned short* Ob    = ws + 3 * QN;              // 8 MB
    unsigned short* WoT   = ws + 4 * QN;              // 2 MB
    unsigned short* WqkvT = ws + 4 * QN + (size_t)D_ * D_;  // 384 KB

    k_transpose_wo<<<dim3(16, 16), 256, 0, stream>>>(Wo, WoT);
    k_transpose_w<<<dim3(H_, 3), 256, 0, stream>>>(Wq, Wk, Wv, WqkvT);
    k_qkv<<<dim3(TOK / 128, H_), 256, 0, stream>>>(X, WqkvT, bq, bk, bv, Qb, Kb, Vtb);
    k_attn<<<dim3(32, 32), 256, 0, stream>>>(Qb, Kb, Vtb, Ob);
    k_out<<<dim3(TOK / 64, D_ / 64), 256, 0, stream>>>(Ob, WoT, bo, out);
}

// Round 9
// 169.379 us; speedup vs baseline: 1.9999x; 1.9999x over previous
//
#include <hip/hip_runtime.h>
#include <stdint.h>

#define B_  2
#define S_  2048
#define D_  1024
#define H_  16
#define HD_ 64
#define TOK (B_*S_)   // 4096

typedef __bf16 bf16x8 __attribute__((ext_vector_type(8)));
typedef __bf16 bf16x4 __attribute__((ext_vector_type(4)));
typedef float  f32x4  __attribute__((ext_vector_type(4)));

static_assert(sizeof(bf16x8) == 16, "bf16x8 must be 16B");
static_assert(sizeof(bf16x4) == 8,  "bf16x4 must be 8B");

__device__ __forceinline__ float fexp2(float x) { return __builtin_amdgcn_exp2f(x); }

__device__ __forceinline__ f32x4 mfma16(bf16x8 a, bf16x8 b, f32x4 c) {
    return __builtin_amdgcn_mfma_f32_16x16x32_bf16(a, b, c, 0, 0, 0);
}

// ---------------------------------------------------------------------------
// K0a: Wo [1024(in)][1024(out)] fp32 -> WoT [out][in] bf16. grid (16,16).
// ---------------------------------------------------------------------------
__global__ __launch_bounds__(256) void k_transpose_wo(
    const float* __restrict__ Wo, unsigned short* __restrict__ WoT)
{
    __shared__ float t[64][65];
    const int i0 = blockIdx.x * 64;
    const int o0 = blockIdx.y * 64;
    const int tid = threadIdx.x;
    #pragma unroll
    for (int p = 0; p < 16; ++p) {
        int idx = tid + p * 256;
        int r = idx >> 6, c = idx & 63;
        t[r][c] = Wo[(size_t)(i0 + r) * D_ + o0 + c];
    }
    __syncthreads();
    #pragma unroll
    for (int p = 0; p < 16; ++p) {
        int idx = tid + p * 256;
        int r = idx >> 6, c = idx & 63;
        reinterpret_cast<__bf16*>(WoT)[(size_t)(o0 + r) * D_ + i0 + c] = (__bf16)t[c][r];
    }
}

// ---------------------------------------------------------------------------
// K0b: Wq/Wk/Wv [H][d][e] fp32 -> WT [z][h][e][d] bf16. grid (H,3), block 256.
// ---------------------------------------------------------------------------
__global__ __launch_bounds__(256) void k_transpose_w(
    const float* __restrict__ Wq, const float* __restrict__ Wk,
    const float* __restrict__ Wv, unsigned short* __restrict__ WT)
{
    __shared__ float t[64][65];
    const int h = blockIdx.x, z = blockIdx.y;
    const float* W = (z == 0) ? Wq : (z == 1) ? Wk : Wv;
    const int tid = threadIdx.x;
    #pragma unroll
    for (int p = 0; p < 4; ++p) {
        int idx = tid + p * 256;
        int r = idx >> 4, c4 = (idx & 15) * 4;
        *reinterpret_cast<float4*>(&t[r][c4]) =
            *reinterpret_cast<const float4*>(&W[h * 4096 + r * 64 + c4]);
    }
    __syncthreads();
    const int e = tid >> 2, db = (tid & 3) * 16;
    __bf16* out = reinterpret_cast<__bf16*>(WT) + ((size_t)(z * H_ + h) * 64 + e) * 64 + db;
    #pragma unroll
    for (int jj = 0; jj < 2; ++jj) {
        bf16x8 v;
        #pragma unroll
        for (int j = 0; j < 8; ++j) v[j] = (__bf16)t[db + jj * 8 + j][e];
        *reinterpret_cast<bf16x8*>(out + jj * 8) = v;
    }
}

// ---------------------------------------------------------------------------
// K1 (v3, unchanged): QKV projection, fused z-loop, MFMA.
// grid (TOK/128, H), block 256.
// ---------------------------------------------------------------------------
__global__ __launch_bounds__(256) void k_qkv(
    const float* __restrict__ X, const unsigned short* __restrict__ WT,
    const float* __restrict__ bq, const float* __restrict__ bk,
    const float* __restrict__ bv,
    unsigned short* __restrict__ Qo, unsigned short* __restrict__ Ko,
    unsigned short* __restrict__ Vt)
{
    __shared__ unsigned short Xl[128 * 64];
    __shared__ unsigned short Wl[3][64 * 64];

    const int tid  = threadIdx.x;
    const int lane = tid & 63, w = tid >> 6;
    const int g = lane >> 4, q = lane & 15;
    const int tok0 = blockIdx.x * 128;
    const int h    = blockIdx.y;

    #pragma unroll
    for (int i = 0; i < 4; ++i) {
        int c = tid + 256 * i;
        int row = c >> 3, slot = c & 7;
        const float* src = &X[(size_t)(tok0 + row) * D_ + h * HD_ + slot * 8];
        float4 x0 = *reinterpret_cast<const float4*>(src);
        float4 x1 = *reinterpret_cast<const float4*>(src + 4);
        bf16x8 v = { (__bf16)x0.x, (__bf16)x0.y, (__bf16)x0.z, (__bf16)x0.w,
                     (__bf16)x1.x, (__bf16)x1.y, (__bf16)x1.z, (__bf16)x1.w };
        *reinterpret_cast<bf16x8*>(
            reinterpret_cast<char*>(Xl) + row * 128 + ((slot ^ (row & 7)) * 16)) = v;
    }
    #pragma unroll
    for (int zz = 0; zz < 3; ++zz) {
        #pragma unroll
        for (int i = 0; i < 2; ++i) {
            int c = tid + 256 * i;
            int e = c >> 3, slot = c & 7;
            bf16x8 v = *reinterpret_cast<const bf16x8*>(
                &WT[((size_t)(zz * H_ + h) * 64 + e) * 64 + slot * 8]);
            *reinterpret_cast<bf16x8*>(
                reinterpret_cast<char*>(Wl[zz]) + e * 128 + ((slot ^ (e & 7)) * 16)) = v;
        }
    }
    __syncthreads();

    const float scq = 0.18033688011112042f;  // log2(e)/8
    const int b  = tok0 >> 11;
    const int sb = (tok0 & (S_ - 1)) + w * 32;

    #pragma unroll
    for (int z = 0; z < 3; ++z) {
        const float* bb = (z == 0) ? bq : (z == 1) ? bk : bv;
        f32x4 acc[2][4] = {};
        #pragma unroll
        for (int s = 0; s < 2; ++s) {
            bf16x8 af[2], bfr[4];
            #pragma unroll
            for (int am = 0; am < 2; ++am) {
                int row  = w * 32 + am * 16 + q;
                int slot = (s * 4 + g) ^ (row & 7);
                af[am] = *reinterpret_cast<const bf16x8*>(
                    reinterpret_cast<const char*>(Xl) + row * 128 + slot * 16);
            }
            #pragma unroll
            for (int bn = 0; bn < 4; ++bn) {
                int row  = bn * 16 + q;
                int slot = (s * 4 + g) ^ (row & 7);
                bfr[bn] = *reinterpret_cast<const bf16x8*>(
                    reinterpret_cast<const char*>(Wl[z]) + row * 128 + slot * 16);
            }
            if (z == 2) {
                #pragma unroll
                for (int am = 0; am < 2; ++am)
                    #pragma unroll
                    for (int bn = 0; bn < 4; ++bn)
                        acc[am][bn] = mfma16(af[am], bfr[bn], acc[am][bn]);
            } else {
                #pragma unroll
                for (int am = 0; am < 2; ++am)
                    #pragma unroll
                    for (int bn = 0; bn < 4; ++bn)
                        acc[am][bn] = mfma16(bfr[bn], af[am], acc[am][bn]);
            }
        }
        if (z == 2) {
            #pragma unroll
            for (int bn = 0; bn < 4; ++bn) {
                int e = bn * 16 + q;
                float bia = bb[h * HD_ + e];
                #pragma unroll
                for (int am = 0; am < 2; ++am) {
                    int s4 = sb + am * 16 + 4 * g;
                    bf16x4 ov = { (__bf16)(acc[am][bn][0] + bia), (__bf16)(acc[am][bn][1] + bia),
                                  (__bf16)(acc[am][bn][2] + bia), (__bf16)(acc[am][bn][3] + bia) };
                    *reinterpret_cast<bf16x4*>(
                        &Vt[((size_t)(b * H_ + h) * HD_ + e) * S_ + s4]) = ov;
                }
            }
        } else {
            const float sc = (z == 0) ? scq : 1.0f;
            unsigned short* dst = (z == 0) ? Qo : Ko;
            #pragma unroll
            for (int bn = 0; bn < 4; ++bn) {
                float4 bia4 = *reinterpret_cast<const float4*>(&bb[h * HD_ + bn * 16 + 4 * g]);
                #pragma unroll
                for (int am = 0; am < 2; ++am) {
                    int tok = sb + am * 16 + q;
                    bf16x4 ov = { (__bf16)((acc[am][bn][0] + bia4.x) * sc),
                                  (__bf16)((acc[am][bn][1] + bia4.y) * sc),
                                  (__bf16)((acc[am][bn][2] + bia4.z) * sc),
                                  (__bf16)((acc[am][bn][3] + bia4.w) * sc) };
                    *reinterpret_cast<bf16x4*>(
                        &dst[((size_t)(b * H_ + h) * S_ + tok) * HD_ + bn * 16 + 4 * g]) = ov;
                }
            }
        }
    }
}

// ---------------------------------------------------------------------------
// K2 (v6): flash attention = r4's PROVEN 256-thr/4-wave/16q skeleton + ONE
// change: K-row-permuted staging (rho) so QK^T output regs ARE the PV
// B-fragment -> P_lds roundtrip deleted (in-register P).
//  rho(8g+j)=4g+j, rho(8g+4+j)=16+4g+j  (bijective; C/D map col=lane&15,
//  row=4*(lane>>4)+reg). lane(g,q) holds keys 8g..8g+7 for query-col q.
// Double-buffered K/V, 1 barrier/iter, defer-max (T13), setprio (T5),
// XCD-grouped bh map. grid (32,32), block 256.
// ---------------------------------------------------------------------------
__global__ __launch_bounds__(256) void k_attn(
    const unsigned short* __restrict__ Q,
    const unsigned short* __restrict__ K,
    const unsigned short* __restrict__ V,
    unsigned short* __restrict__ O)
{
    __shared__ unsigned short K_lds[2][32 * 72];  // permuted rows, +8 pad
    __shared__ unsigned short V_lds[2][64 * 40];  // [dim][key], +8 pad

    const int L  = blockIdx.x + (int)gridDim.x * blockIdx.y;  // 0..1023
    const int bh = (L & 7) * 4 + ((L >> 3) & 3);              // XCD-grouped
    const int sb = L >> 5;                                    // q-tile (64 q)

    const unsigned short* Qp = Q + (size_t)bh * S_ * HD_;
    const unsigned short* Kp = K + (size_t)bh * S_ * HD_;
    const unsigned short* Vp = V + (size_t)bh * HD_ * S_;

    const int tid  = threadIdx.x;
    const int lane = tid & 63, w = tid >> 6;      // 4 waves
    const int g = lane >> 4, q = lane & 15;
    const int q0 = sb * 64 + w * 16;

    bf16x8 qf0 = *reinterpret_cast<const bf16x8*>(&Qp[(size_t)(q0 + q) * HD_ + 8 * g]);
    bf16x8 qf1 = *reinterpret_cast<const bf16x8*>(&Qp[(size_t)(q0 + q) * HD_ + 32 + 8 * g]);

    f32x4 acc0 = {0.f, 0.f, 0.f, 0.f}, acc1 = acc0, acc2 = acc0, acc3 = acc0;
    float m = -3.0e38f, lp = 0.0f;

    // staging maps (256 threads, full coverage — r4-verified):
    // K: 32 rows x 8 chunks of 8 elems; V: 64 rows x 4 chunks of 8 elems.
    const int kr = tid >> 3, ks = (tid & 7) * 8;
    const int vr = tid >> 2, vs = (tid & 3) * 8;
    // permuted LDS row for key kr
    const int krp = (kr & 4) ? (16 + 4 * (kr >> 3) + (kr & 3))
                             : (4 * (kr >> 3) + (kr & 3));

    const unsigned short* kSrc = Kp + (size_t)kr * HD_ + ks;  // += 32*HD_ per tile
    const unsigned short* vSrc = Vp + (size_t)vr * S_  + vs;  // += 32 per tile

    {
        uint4 k0 = *reinterpret_cast<const uint4*>(kSrc);
        uint4 v0 = *reinterpret_cast<const uint4*>(vSrc);
        *reinterpret_cast<uint4*>(&K_lds[0][krp * 72 + ks]) = k0;
        *reinterpret_cast<uint4*>(&V_lds[0][vr * 40 + vs])  = v0;
    }
    __syncthreads();

    const int NT = S_ / 32;   // 64 tiles
    for (int t = 0; t < NT; ++t) {
        const int cur = t & 1, nxt = cur ^ 1;

        uint4 kn, vn;
        const bool more = (t + 1 < NT);
        if (more) {
            kn = *reinterpret_cast<const uint4*>(kSrc + (size_t)(t + 1) * 32 * HD_);
            vn = *reinterpret_cast<const uint4*>(vSrc + (size_t)(t + 1) * 32);
        }

        const unsigned short* Kb = K_lds[cur];
        const unsigned short* Vb = V_lds[cur];
        bf16x8 k00 = *reinterpret_cast<const bf16x8*>(&Kb[q * 72 + 8 * g]);
        bf16x8 k01 = *reinterpret_cast<const bf16x8*>(&Kb[q * 72 + 32 + 8 * g]);
        bf16x8 k10 = *reinterpret_cast<const bf16x8*>(&Kb[(16 + q) * 72 + 8 * g]);
        bf16x8 k11 = *reinterpret_cast<const bf16x8*>(&Kb[(16 + q) * 72 + 32 + 8 * g]);
        bf16x8 vf0 = *reinterpret_cast<const bf16x8*>(&Vb[(0 * 16 + q) * 40 + 8 * g]);
        bf16x8 vf1 = *reinterpret_cast<const bf16x8*>(&Vb[(1 * 16 + q) * 40 + 8 * g]);
        bf16x8 vf2 = *reinterpret_cast<const bf16x8*>(&Vb[(2 * 16 + q) * 40 + 8 * g]);
        bf16x8 vf3 = *reinterpret_cast<const bf16x8*>(&Vb[(3 * 16 + q) * 40 + 8 * g]);

        // S^T = K.Q^T with permuted A-rows: lane(g,q) gets keys 8g..8g+3 (s0)
        // and 8g+4..8g+7 (s1) for query-column q.
        f32x4 z4 = {0.f, 0.f, 0.f, 0.f};
        __builtin_amdgcn_s_setprio(1);
        f32x4 s0 = mfma16(k00, qf0, z4); s0 = mfma16(k01, qf1, s0);
        f32x4 s1 = mfma16(k10, qf0, z4); s1 = mfma16(k11, qf1, s1);
        __builtin_amdgcn_s_setprio(0);

        // online softmax, defer-max fast path
        float pmax = fmaxf(fmaxf(fmaxf(s0[0], s0[1]), fmaxf(s0[2], s0[3])),
                           fmaxf(fmaxf(s1[0], s1[1]), fmaxf(s1[2], s1[3])));
        if (!__all(pmax - m <= 8.0f)) {
            float pm = pmax;
            pm = fmaxf(pm, __shfl_xor(pm, 16));
            pm = fmaxf(pm, __shfl_xor(pm, 32));
            float mn  = fmaxf(m, pm);
            float scl = fexp2(m - mn);
            m = mn;
            lp *= scl;
            acc0 *= scl; acc1 *= scl; acc2 *= scl; acc3 *= scl;
        }
        float p0 = fexp2(s0[0] - m), p1 = fexp2(s0[1] - m);
        float p2 = fexp2(s0[2] - m), p3 = fexp2(s0[3] - m);
        float p4 = fexp2(s1[0] - m), p5 = fexp2(s1[1] - m);
        float p6 = fexp2(s1[2] - m), p7 = fexp2(s1[3] - m);
        lp += ((p0 + p1) + (p2 + p3)) + ((p4 + p5) + (p6 + p7));

        // P entirely in registers: keys 8g..8g+7 in order = PV B-fragment
        bf16x8 pf = { (__bf16)p0, (__bf16)p1, (__bf16)p2, (__bf16)p3,
                      (__bf16)p4, (__bf16)p5, (__bf16)p6, (__bf16)p7 };

        __builtin_amdgcn_s_setprio(1);
        acc0 = mfma16(vf0, pf, acc0);
        acc1 = mfma16(vf1, pf, acc1);
        acc2 = mfma16(vf2, pf, acc2);
        acc3 = mfma16(vf3, pf, acc3);
        __builtin_amdgcn_s_setprio(0);

        if (more) {
            *reinterpret_cast<uint4*>(&K_lds[nxt][krp * 72 + ks]) = kn;
            *reinterpret_cast<uint4*>(&V_lds[nxt][vr * 40 + vs])  = vn;
        }
        __syncthreads();
    }

    // ---- epilogue: reduce l over g (lanes q, q+16, q+32, q+48), write O ----
    lp += __shfl_xor(lp, 16);
    lp += __shfl_xor(lp, 32);
    const float inv = 1.0f / lp;
    const int b = bh >> 4, h = bh & 15;
    __bf16* Ob = reinterpret_cast<__bf16*>(O);
    size_t row = (size_t)(b * S_ + q0 + q) * D_ + h * HD_ + 4 * g;
    bf16x4 o0 = { (__bf16)(acc0[0]*inv), (__bf16)(acc0[1]*inv),
                  (__bf16)(acc0[2]*inv), (__bf16)(acc0[3]*inv) };
    bf16x4 o1 = { (__bf16)(acc1[0]*inv), (__bf16)(acc1[1]*inv),
                  (__bf16)(acc1[2]*inv), (__bf16)(acc1[3]*inv) };
    bf16x4 o2 = { (__bf16)(acc2[0]*inv), (__bf16)(acc2[1]*inv),
                  (__bf16)(acc2[2]*inv), (__bf16)(acc2[3]*inv) };
    bf16x4 o3 = { (__bf16)(acc3[0]*inv), (__bf16)(acc3[1]*inv),
                  (__bf16)(acc3[2]*inv), (__bf16)(acc3[3]*inv) };
    *reinterpret_cast<bf16x4*>(&Ob[row + 0])  = o0;
    *reinterpret_cast<bf16x4*>(&Ob[row + 16]) = o1;
    *reinterpret_cast<bf16x4*>(&Ob[row + 32]) = o2;
    *reinterpret_cast<bf16x4*>(&Ob[row + 48]) = o3;
}

// ---------------------------------------------------------------------------
// K3 (v3, unchanged): out = O_attn(bf16) @ WoT + bo, fp32. 64x64 tile, BK=64,
// dbuf swizzled LDS. grid (64,16), block 256.
// ---------------------------------------------------------------------------
__global__ __launch_bounds__(256) void k_out(
    const unsigned short* __restrict__ A,
    const unsigned short* __restrict__ Wt,
    const float* __restrict__ bo,
    float* __restrict__ C)
{
    __shared__ unsigned short Al[2][64 * 64];
    __shared__ unsigned short Bl[2][64 * 64];

    const int tid  = threadIdx.x;
    const int lane = tid & 63, w = tid >> 6;
    const int g = lane >> 4, q = lane & 15;
    const int wr = w & 1, wc = w >> 1;
    const int m0 = blockIdx.x * 64;
    const int n0 = blockIdx.y * 64;

    int    sbyte[2];
    size_t sgA[2], sgB[2];
    #pragma unroll
    for (int i = 0; i < 2; ++i) {
        int c = tid + 256 * i;
        int row = c >> 3, slot = c & 7;
        sbyte[i] = row * 128 + ((slot ^ (row & 7)) * 16);
        sgA[i] = (size_t)(m0 + row) * D_ + slot * 8;
        sgB[i] = (size_t)(n0 + row) * D_ + slot * 8;
    }

    uint4 ra[2], rb[2];
    #pragma unroll
    for (int i = 0; i < 2; ++i) {
        ra[i] = *reinterpret_cast<const uint4*>(A  + sgA[i]);
        rb[i] = *reinterpret_cast<const uint4*>(Wt + sgB[i]);
    }
    #pragma unroll
    for (int i = 0; i < 2; ++i) {
        *reinterpret_cast<uint4*>(reinterpret_cast<char*>(Al[0]) + sbyte[i]) = ra[i];
        *reinterpret_cast<uint4*>(reinterpret_cast<char*>(Bl[0]) + sbyte[i]) = rb[i];
    }
    __syncthreads();

    f32x4 acc[2][2] = {};
    const int NKT = D_ / 64;   // 16
    for (int kt = 0; kt < NKT; ++kt) {
        const int cur = kt & 1, nxt = cur ^ 1;
        const bool more = (kt + 1 < NKT);
        if (more) {
            #pragma unroll
            for (int i = 0; i < 2; ++i) {
                ra[i] = *reinterpret_cast<const uint4*>(A  + sgA[i] + (kt + 1) * 64);
                rb[i] = *reinterpret_cast<const uint4*>(Wt + sgB[i] + (kt + 1) * 64);
            }
        }
        const char* Ab = reinterpret_cast<const char*>(Al[cur]);
        const char* Bb = reinterpret_cast<const char*>(Bl[cur]);
        #pragma unroll
        for (int s = 0; s < 2; ++s) {
            bf16x8 af[2], bfr[2];
            #pragma unroll
            for (int am = 0; am < 2; ++am) {
                int row  = wr * 32 + am * 16 + q;
                int slot = (s * 4 + g) ^ (row & 7);
                af[am] = *reinterpret_cast<const bf16x8*>(Ab + row * 128 + slot * 16);
            }
            #pragma unroll
            for (int bn = 0; bn < 2; ++bn) {
                int row  = wc * 32 + bn * 16 + q;
                int slot = (s * 4 + g) ^ (row & 7);
                bfr[bn] = *reinterpret_cast<const bf16x8*>(Bb + row * 128 + slot * 16);
            }
            #pragma unroll
            for (int am = 0; am < 2; ++am)
                #pragma unroll
                for (int bn = 0; bn < 2; ++bn)
                    acc[am][bn] = mfma16(af[am], bfr[bn], acc[am][bn]);
        }
        if (more) {
            #pragma unroll
            for (int i = 0; i < 2; ++i) {
                *reinterpret_cast<uint4*>(reinterpret_cast<char*>(Al[nxt]) + sbyte[i]) = ra[i];
                *reinterpret_cast<uint4*>(reinterpret_cast<char*>(Bl[nxt]) + sbyte[i]) = rb[i];
            }
        }
        __syncthreads();
    }

    #pragma unroll
    for (int bn = 0; bn < 2; ++bn) {
        int n = n0 + wc * 32 + bn * 16 + q;
        float bia = bo[n];
        #pragma unroll
        for (int am = 0; am < 2; ++am) {
            int mbase = m0 + wr * 32 + am * 16 + 4 * g;
            #pragma unroll
            for (int j = 0; j < 4; ++j)
                C[(size_t)(mbase + j) * D_ + n] = acc[am][bn][j] + bia;
        }
    }
}

// ---------------------------------------------------------------------------
extern "C" void kernel_launch(void* const* d_in, const int* in_sizes, int n_in,
                              void* d_out, int out_size, void* d_ws, size_t ws_size,
                              hipStream_t stream)
{
    const float* X  = (const float*)d_in[0];
    const float* Wq = (const float*)d_in[1];
    const float* bq = (const float*)d_in[2];
    const float* Wk = (const float*)d_in[3];
    const float* bk = (const float*)d_in[4];
    const float* Wv = (const float*)d_in[5];
    const float* bv = (const float*)d_in[6];
    const float* Wo = (const float*)d_in[7];
    const float* bo = (const float*)d_in[8];
    float* out = (float*)d_out;

    unsigned short* ws = (unsigned short*)d_ws;
    const size_t QN = (size_t)B_ * H_ * S_ * HD_;     // 4M elements
    unsigned short* Qb    = ws;                       // 8 MB
    unsigned short* Kb    = ws + QN;                  // 8 MB
    unsigned short* Vtb   = ws + 2 * QN;              // 8 MB
    unsigned short* Ob    = ws + 3 * QN;              // 8 MB
    unsigned short* WoT   = ws + 4 * QN;              // 2 MB
    unsigned short* WqkvT = ws + 4 * QN + (size_t)D_ * D_;  // 384 KB

    k_transpose_wo<<<dim3(16, 16), 256, 0, stream>>>(Wo, WoT);
    k_transpose_w<<<dim3(H_, 3), 256, 0, stream>>>(Wq, Wk, Wv, WqkvT);
    k_qkv<<<dim3(TOK / 128, H_), 256, 0, stream>>>(X, WqkvT, bq, bk, bv, Qb, Kb, Vtb);
    k_attn<<<dim3(32, 32), 256, 0, stream>>>(Qb, Kb, Vtb, Ob);
    k_out<<<dim3(TOK / 64, D_ / 64), 256, 0, stream>>>(Ob, WoT, bo, out);
}